// Round 8
// baseline (367.376 us; speedup 1.0000x reference)
//
#include <hip/hip_runtime.h>
#include <math.h>

#define HH 64
#define SCAN_B 1024

// ---------------- CSR build ----------------

__global__ void k_zero_int(int* __restrict__ p, int n) {
    int i = blockIdx.x * blockDim.x + threadIdx.x;
    if (i < n) p[i] = 0;
}

__global__ void k_zero_float(float* __restrict__ p, int n) {
    int i = blockIdx.x * blockDim.x + threadIdx.x;
    if (i < n) p[i] = 0.f;
}

__global__ void k_count(const int* __restrict__ col, int E, int* __restrict__ cnt) {
    int e = blockIdx.x * blockDim.x + threadIdx.x;
    if (e < E) atomicAdd(&cnt[col[e]], 1);
}

__global__ void k_scan_reduce(const int* __restrict__ cnt, int n, int* __restrict__ partial) {
    int i = blockIdx.x * SCAN_B + threadIdx.x;
    int v = (i < n) ? cnt[i] : 0;
#pragma unroll
    for (int off = 1; off < 64; off <<= 1) v += __shfl_xor(v, off, 64);
    __shared__ int ws[SCAN_B / 64];
    if ((threadIdx.x & 63) == 0) ws[threadIdx.x >> 6] = v;
    __syncthreads();
    if (threadIdx.x == 0) {
        int s = 0;
#pragma unroll
        for (int j = 0; j < SCAN_B / 64; ++j) s += ws[j];
        partial[blockIdx.x] = s;
    }
}

__global__ void k_scan_partials(int* __restrict__ partial, int nb, int* __restrict__ rowptr, int n) {
    __shared__ int buf[1024];
    int tid = threadIdx.x;
    int orig = (tid < nb) ? partial[tid] : 0;
    buf[tid] = orig;
    __syncthreads();
#pragma unroll
    for (int off = 1; off < 1024; off <<= 1) {
        int t = (tid >= off) ? buf[tid - off] : 0;
        __syncthreads();
        buf[tid] += t;
        __syncthreads();
    }
    if (tid < nb) partial[tid] = buf[tid] - orig;
    if (tid == nb - 1) rowptr[n] = buf[tid];
}

// also inits head = -1 for the linked-list build
__global__ void k_scan_apply(const int* __restrict__ cnt, const int* __restrict__ partial,
                             int n, int* __restrict__ rowptr, int* __restrict__ head,
                             float* __restrict__ dinv) {
    __shared__ int buf[SCAN_B];
    int tid = threadIdx.x;
    int i = blockIdx.x * SCAN_B + tid;
    int orig = (i < n) ? cnt[i] : 0;
    buf[tid] = orig;
    __syncthreads();
#pragma unroll
    for (int off = 1; off < SCAN_B; off <<= 1) {
        int t = (tid >= off) ? buf[tid - off] : 0;
        __syncthreads();
        buf[tid] += t;
        __syncthreads();
    }
    if (i < n) {
        int excl = buf[tid] - orig + partial[blockIdx.x];
        rowptr[i] = excl;
        head[i]   = -1;
        dinv[i]   = rsqrtf((float)(orig + 1));
    }
}

// linked-list build: only sequential writes (next) + small L2-resident atomics (head)
__global__ void k_link(const int* __restrict__ col, int E,
                       int* __restrict__ head, int* __restrict__ next) {
    int e = blockIdx.x * blockDim.x + threadIdx.x;
    if (e >= E) return;
    int c = col[e];
    int prev = atomicExch(&head[c], e);
    next[e] = prev;
}

// node-parallel walk: random L2-hot reads, SEQUENTIAL csr writes (no line bouncing)
__global__ void k_walk(const int* __restrict__ row, const int* __restrict__ head,
                       const int* __restrict__ next, const int* __restrict__ rowptr,
                       const float* __restrict__ dinv, int2* __restrict__ csr, int n) {
    int node = blockIdx.x * blockDim.x + threadIdx.x;
    if (node >= n) return;
    int p = head[node];
    int dst = rowptr[node];
    float dc = dinv[node];
    while (p >= 0) {
        int r = row[p];
        csr[dst++] = make_int2(r, __float_as_int(dinv[r] * dc));
        p = next[p];
    }
}

// ---------------- dense transform: k-chunked register-tiled GEMM ----------------
template<int FIN>
__global__ __launch_bounds__(256, 4) void k_gemm2(const float* __restrict__ x,
                                                  const float* __restrict__ W,
                                                  float* __restrict__ lin, int n) {
    constexpr int KC = 32;
    constexpr int XS = 68;
    __shared__ __align__(16) float Ws[FIN][HH];
    __shared__ __align__(16) float xs_t[KC][XS];
    const int tid = threadIdx.x;
    const int tx = tid & 15;
    const int ty = tid >> 4;
    const int node0 = blockIdx.x * 64;

    for (int i = tid * 4; i < FIN * HH; i += 1024)
        *(float4*)&Ws[0][i] = *(const float4*)&W[i];

    float acc[4][4] = {};

    const int rr0 = tid >> 3;
    const int cc  = (tid & 7) * 4;

    for (int kc = 0; kc < FIN; kc += KC) {
        __syncthreads();
        for (int rr = rr0; rr < 64; rr += 32) {
            float4 v = make_float4(0.f, 0.f, 0.f, 0.f);
            if (node0 + rr < n) v = *(const float4*)&x[(size_t)(node0 + rr) * FIN + kc + cc];
            xs_t[cc + 0][rr] = v.x;
            xs_t[cc + 1][rr] = v.y;
            xs_t[cc + 2][rr] = v.z;
            xs_t[cc + 3][rr] = v.w;
        }
        __syncthreads();
#pragma unroll 4
        for (int k = 0; k < KC; ++k) {
            float4 a4 = *(const float4*)&xs_t[k][ty * 4];
            float4 b4 = *(const float4*)&Ws[kc + k][tx * 4];
            acc[0][0] = fmaf(a4.x, b4.x, acc[0][0]);
            acc[0][1] = fmaf(a4.x, b4.y, acc[0][1]);
            acc[0][2] = fmaf(a4.x, b4.z, acc[0][2]);
            acc[0][3] = fmaf(a4.x, b4.w, acc[0][3]);
            acc[1][0] = fmaf(a4.y, b4.x, acc[1][0]);
            acc[1][1] = fmaf(a4.y, b4.y, acc[1][1]);
            acc[1][2] = fmaf(a4.y, b4.z, acc[1][2]);
            acc[1][3] = fmaf(a4.y, b4.w, acc[1][3]);
            acc[2][0] = fmaf(a4.z, b4.x, acc[2][0]);
            acc[2][1] = fmaf(a4.z, b4.y, acc[2][1]);
            acc[2][2] = fmaf(a4.z, b4.z, acc[2][2]);
            acc[2][3] = fmaf(a4.z, b4.w, acc[2][3]);
            acc[3][0] = fmaf(a4.w, b4.x, acc[3][0]);
            acc[3][1] = fmaf(a4.w, b4.y, acc[3][1]);
            acc[3][2] = fmaf(a4.w, b4.z, acc[3][2]);
            acc[3][3] = fmaf(a4.w, b4.w, acc[3][3]);
        }
    }

#pragma unroll
    for (int i = 0; i < 4; ++i) {
        int node = node0 + ty * 4 + i;
        if (node < n) *(float4*)&lin[(size_t)node * HH + tx * 4] = *(float4*)acc[i];
    }
}

// ---------------- gather aggregation + bias + L2norm + ReLU ----------------
__global__ void k_gather(const float* __restrict__ lin, const int2* __restrict__ csr,
                         const int* __restrict__ rowptr,
                         const float* __restrict__ dinv, const float* __restrict__ b,
                         float* __restrict__ hout, int n) {
    int node = blockIdx.x * (blockDim.x >> 6) + (threadIdx.x >> 6);
    int lane = threadIdx.x & 63;
    if (node >= n) return;
    int start = rowptr[node], end = rowptr[node + 1];
    float di = dinv[node];
    float acc0 = di * di * lin[(size_t)node * HH + lane];   // self-loop
    float acc1 = 0.f, acc2 = 0.f, acc3 = 0.f;
    for (int base = start; base < end; base += 64) {
        int m = end - base; if (m > 64) m = 64;
        int2 ev = (base + lane < end) ? csr[base + lane] : make_int2(0, 0);
        int   sv = ev.x;
        float wv = __int_as_float(ev.y);
        int j = 0;
        for (; j + 3 < m; j += 4) {
            int s0 = __shfl(sv, j, 64);     float w0 = __shfl(wv, j, 64);
            int s1 = __shfl(sv, j + 1, 64); float w1 = __shfl(wv, j + 1, 64);
            int s2 = __shfl(sv, j + 2, 64); float w2 = __shfl(wv, j + 2, 64);
            int s3 = __shfl(sv, j + 3, 64); float w3 = __shfl(wv, j + 3, 64);
            float v0 = lin[(size_t)s0 * HH + lane];
            float v1 = lin[(size_t)s1 * HH + lane];
            float v2 = lin[(size_t)s2 * HH + lane];
            float v3 = lin[(size_t)s3 * HH + lane];
            acc0 = fmaf(w0, v0, acc0);
            acc1 = fmaf(w1, v1, acc1);
            acc2 = fmaf(w2, v2, acc2);
            acc3 = fmaf(w3, v3, acc3);
        }
        for (; j < m; ++j) {
            int s0 = __shfl(sv, j, 64); float w0 = __shfl(wv, j, 64);
            acc0 = fmaf(w0, lin[(size_t)s0 * HH + lane], acc0);
        }
    }
    float v = (acc0 + acc1) + (acc2 + acc3);
    v += b[lane];
    float ss = v * v;
#pragma unroll
    for (int off = 1; off < 64; off <<= 1) ss += __shfl_xor(ss, off, 64);
    v = v / fmaxf(sqrtf(ss), 1e-12f);
    hout[(size_t)node * HH + lane] = fmaxf(v, 0.f);
}

// ---------------- pooling: parallel over nodes ----------------
__global__ __launch_bounds__(256) void k_pool(const float* __restrict__ node_emb,
                                              const int* __restrict__ batch,
                                              float* __restrict__ sums,
                                              float* __restrict__ cnts, int n) {
    const int NPW = 16;
    int wave = blockIdx.x * 4 + (threadIdx.x >> 6);
    int lane = threadIdx.x & 63;
    int start = wave * NPW;
    if (start >= n) return;
    int end = start + NPW; if (end > n) end = n;
    int cur = batch[start];
    float acc = 0.f;
    int runlen = 0;
    for (int node = start; node < end; ++node) {
        int g = batch[node];
        if (g != cur) {
            atomicAdd(&sums[(size_t)cur * HH + lane], acc);
            if (lane == 0) atomicAdd(&cnts[cur], (float)runlen);
            acc = 0.f; runlen = 0; cur = g;
        }
        acc += node_emb[(size_t)node * HH + lane];
        ++runlen;
    }
    atomicAdd(&sums[(size_t)cur * HH + lane], acc);
    if (lane == 0) atomicAdd(&cnts[cur], (float)runlen);
}

// ---------------- classifier + softmax ----------------
__global__ void k_final2(const float* __restrict__ sums, const float* __restrict__ cnts,
                         const float* __restrict__ Wm, const float* __restrict__ bm,
                         float* __restrict__ logits, float* __restrict__ probs,
                         float* __restrict__ graph_emb) {
    int g = blockIdx.x;
    int lane = threadIdx.x;
    float mean = sums[(size_t)g * HH + lane] / fmaxf(cnts[g], 1.0f);
    graph_emb[(size_t)g * HH + lane] = mean;

    __shared__ float semb[HH];
    __shared__ float slog[16];
    semb[lane] = mean;
    __syncthreads();
    if (lane < 10) {
        float acc = bm[lane];
        for (int k = 0; k < HH; ++k) acc = fmaf(semb[k], Wm[k * 10 + lane], acc);
        slog[lane] = acc;
    }
    __syncthreads();
    if (lane < 10) {
        float mx = -1e30f;
        for (int j = 0; j < 10; ++j) mx = fmaxf(mx, slog[j]);
        float den = 0.f;
        for (int j = 0; j < 10; ++j) den += __expf(slog[j] - mx);
        float lg = slog[lane];
        logits[g * 10 + lane] = lg;
        probs[g * 10 + lane] = __expf(lg - mx) / den;
    }
}

// ---------------- launch ----------------

extern "C" void kernel_launch(void* const* d_in, const int* in_sizes, int n_in,
                              void* d_out, int out_size, void* d_ws, size_t ws_size,
                              hipStream_t stream) {
    const float* x     = (const float*)d_in[0];
    const int*   ei    = (const int*)  d_in[1];
    const int*   batch = (const int*)  d_in[2];
    const float* W1 = (const float*)d_in[3];  const float* b1 = (const float*)d_in[4];
    const float* W2 = (const float*)d_in[5];  const float* b2 = (const float*)d_in[6];
    const float* W3 = (const float*)d_in[7];  const float* b3 = (const float*)d_in[8];
    const float* Wm = (const float*)d_in[9];  const float* bm = (const float*)d_in[10];

    const int N = in_sizes[2];
    const int E = in_sizes[1] / 2;
    const int G = (out_size - N * HH) / (2 * 10 + HH);

    const int* row = ei;
    const int* col = ei + E;

    float* out       = (float*)d_out;
    float* logits    = out;
    float* probs     = out + (size_t)G * 10;
    float* node_emb  = out + (size_t)2 * G * 10;
    float* graph_emb = node_emb + (size_t)N * HH;

    char* w = (char*)d_ws;
    auto alloc = [&](size_t bytes) { char* p = w; w += (bytes + 255) & ~(size_t)255; return p; };
    float* dinv    = (float*)alloc((size_t)N * 4);
    int*   cnt     = (int*)  alloc((size_t)N * 4);
    int*   rowptr  = (int*)  alloc(((size_t)N + 1) * 4);
    int*   head    = (int*)  alloc((size_t)N * 4);
    int*   nxt     = (int*)  alloc((size_t)E * 4);
    int*   partial = (int*)  alloc(1024 * 4);
    float* sums    = (float*)alloc((size_t)G * HH * 4 + (size_t)G * 4);  // sums + cnts
    float* cnts    = sums + (size_t)G * HH;
    int2*  csr     = (int2*) alloc((size_t)E * 8);
    float* lin     = (float*)alloc((size_t)N * HH * 4);
    float* hbuf    = (float*)alloc((size_t)N * HH * 4);

    const int B = 256;
    dim3 blk(B);
    int node_blocks = (N + 3) / 4;
    int gemm_blocks = (N + 63) / 64;
    int nB = (N + B - 1) / B;
    int eB = (E + B - 1) / B;
    int scanB = (N + SCAN_B - 1) / SCAN_B;
    int poolN = G * HH + G;
    int pool_blocks = (N + 63) / 64;

    // CSR build + normalization
    k_zero_int<<<nB, blk, 0, stream>>>(cnt, N);
    k_zero_float<<<(poolN + B - 1) / B, blk, 0, stream>>>(sums, poolN);
    k_count<<<eB, blk, 0, stream>>>(col, E, cnt);
    k_scan_reduce<<<scanB, dim3(SCAN_B), 0, stream>>>(cnt, N, partial);
    k_scan_partials<<<1, dim3(1024), 0, stream>>>(partial, scanB, rowptr, N);
    k_scan_apply<<<scanB, dim3(SCAN_B), 0, stream>>>(cnt, partial, N, rowptr, head, dinv);
    k_link<<<eB, blk, 0, stream>>>(col, E, head, nxt);
    k_walk<<<nB, blk, 0, stream>>>(row, head, nxt, rowptr, dinv, csr, N);

    // layer 1 (FIN=128)
    k_gemm2<128><<<gemm_blocks, blk, 0, stream>>>(x, W1, lin, N);
    k_gather<<<node_blocks, blk, 0, stream>>>(lin, csr, rowptr, dinv, b1, hbuf, N);
    // layer 2
    k_gemm2<64><<<gemm_blocks, blk, 0, stream>>>(hbuf, W2, lin, N);
    k_gather<<<node_blocks, blk, 0, stream>>>(lin, csr, rowptr, dinv, b2, hbuf, N);
    // layer 3 -> node_emb
    k_gemm2<64><<<gemm_blocks, blk, 0, stream>>>(hbuf, W3, lin, N);
    k_gather<<<node_blocks, blk, 0, stream>>>(lin, csr, rowptr, dinv, b3, node_emb, N);

    // pool + classifier
    k_pool<<<pool_blocks, blk, 0, stream>>>(node_emb, batch, sums, cnts, N);
    k_final2<<<G, dim3(64), 0, stream>>>(sums, cnts, Wm, bm, logits, probs, graph_emb);
}

// Round 10
// 366.279 us; speedup vs baseline: 1.0030x; 1.0030x over previous
//
#include <hip/hip_runtime.h>
#include <math.h>

#define HH 64
#define SCAN_B 1024

// ---------------- init ----------------

__global__ void k_init(int* __restrict__ cnt, int* __restrict__ head,
                       float* __restrict__ sums, int n, int pn) {
    int i = blockIdx.x * blockDim.x + threadIdx.x;
    if (i < n) { cnt[i] = 0; head[i] = -1; }
    if (i < pn) sums[i] = 0.f;
}

// ---------------- CSR build ----------------
// fused degree-count + linked-list build: one pass over col.
__global__ void k_count_link(const int* __restrict__ col, int E,
                             int* __restrict__ cnt, int* __restrict__ head,
                             int* __restrict__ next) {
    int e = blockIdx.x * blockDim.x + threadIdx.x;
    if (e >= E) return;
    int c = col[e];
    atomicAdd(&cnt[c], 1);
    int prev = atomicExch(&head[c], e);
    next[e] = prev;
}

__global__ void k_scan_reduce(const int* __restrict__ cnt, int n, int* __restrict__ partial) {
    int i = blockIdx.x * SCAN_B + threadIdx.x;
    int v = (i < n) ? cnt[i] : 0;
#pragma unroll
    for (int off = 1; off < 64; off <<= 1) v += __shfl_xor(v, off, 64);
    __shared__ int ws[SCAN_B / 64];
    if ((threadIdx.x & 63) == 0) ws[threadIdx.x >> 6] = v;
    __syncthreads();
    if (threadIdx.x == 0) {
        int s = 0;
#pragma unroll
        for (int j = 0; j < SCAN_B / 64; ++j) s += ws[j];
        partial[blockIdx.x] = s;
    }
}

__global__ void k_scan_partials(int* __restrict__ partial, int nb, int* __restrict__ rowptr, int n) {
    __shared__ int buf[1024];
    int tid = threadIdx.x;
    int orig = (tid < nb) ? partial[tid] : 0;
    buf[tid] = orig;
    __syncthreads();
#pragma unroll
    for (int off = 1; off < 1024; off <<= 1) {
        int t = (tid >= off) ? buf[tid - off] : 0;
        __syncthreads();
        buf[tid] += t;
        __syncthreads();
    }
    if (tid < nb) partial[tid] = buf[tid] - orig;
    if (tid == nb - 1) rowptr[n] = buf[tid];
}

__global__ void k_scan_apply(const int* __restrict__ cnt, const int* __restrict__ partial,
                             int n, int* __restrict__ rowptr, float* __restrict__ dinv) {
    __shared__ int buf[SCAN_B];
    int tid = threadIdx.x;
    int i = blockIdx.x * SCAN_B + tid;
    int orig = (i < n) ? cnt[i] : 0;
    buf[tid] = orig;
    __syncthreads();
#pragma unroll
    for (int off = 1; off < SCAN_B; off <<= 1) {
        int t = (tid >= off) ? buf[tid - off] : 0;
        __syncthreads();
        buf[tid] += t;
        __syncthreads();
    }
    if (i < n) {
        rowptr[i] = buf[tid] - orig + partial[blockIdx.x];
        dinv[i]   = rsqrtf((float)(orig + 1));
    }
}

// node-parallel walk: random L2-hot reads, SEQUENTIAL 4B csr writes
__global__ void k_walk(const int* __restrict__ row, const int* __restrict__ head,
                       const int* __restrict__ next, const int* __restrict__ rowptr,
                       int* __restrict__ csr, int n) {
    int node = blockIdx.x * blockDim.x + threadIdx.x;
    if (node >= n) return;
    int p = head[node];
    int dst = rowptr[node];
    while (p >= 0) {
        csr[dst++] = row[p];
        p = next[p];
    }
}

// ---------------- dense transform: k-chunked register-tiled GEMM ----------------
// output pre-scaled by dinv[node] (normalization factorization)
template<int FIN>
__global__ __launch_bounds__(256, 4) void k_gemm2(const float* __restrict__ x,
                                                  const float* __restrict__ W,
                                                  const float* __restrict__ dinv,
                                                  float* __restrict__ linS, int n) {
    constexpr int KC = 32;
    constexpr int XS = 68;
    __shared__ __align__(16) float Ws[FIN][HH];
    __shared__ __align__(16) float xs_t[KC][XS];
    const int tid = threadIdx.x;
    const int tx = tid & 15;
    const int ty = tid >> 4;
    const int node0 = blockIdx.x * 64;

    for (int i = tid * 4; i < FIN * HH; i += 1024)
        *(float4*)&Ws[0][i] = *(const float4*)&W[i];

    float acc[4][4] = {};

    const int rr0 = tid >> 3;
    const int cc  = (tid & 7) * 4;

    for (int kc = 0; kc < FIN; kc += KC) {
        __syncthreads();
        for (int rr = rr0; rr < 64; rr += 32) {
            float4 v = make_float4(0.f, 0.f, 0.f, 0.f);
            if (node0 + rr < n) v = *(const float4*)&x[(size_t)(node0 + rr) * FIN + kc + cc];
            xs_t[cc + 0][rr] = v.x;
            xs_t[cc + 1][rr] = v.y;
            xs_t[cc + 2][rr] = v.z;
            xs_t[cc + 3][rr] = v.w;
        }
        __syncthreads();
#pragma unroll 4
        for (int k = 0; k < KC; ++k) {
            float4 a4 = *(const float4*)&xs_t[k][ty * 4];
            float4 b4 = *(const float4*)&Ws[kc + k][tx * 4];
            acc[0][0] = fmaf(a4.x, b4.x, acc[0][0]);
            acc[0][1] = fmaf(a4.x, b4.y, acc[0][1]);
            acc[0][2] = fmaf(a4.x, b4.z, acc[0][2]);
            acc[0][3] = fmaf(a4.x, b4.w, acc[0][3]);
            acc[1][0] = fmaf(a4.y, b4.x, acc[1][0]);
            acc[1][1] = fmaf(a4.y, b4.y, acc[1][1]);
            acc[1][2] = fmaf(a4.y, b4.z, acc[1][2]);
            acc[1][3] = fmaf(a4.y, b4.w, acc[1][3]);
            acc[2][0] = fmaf(a4.z, b4.x, acc[2][0]);
            acc[2][1] = fmaf(a4.z, b4.y, acc[2][1]);
            acc[2][2] = fmaf(a4.z, b4.z, acc[2][2]);
            acc[2][3] = fmaf(a4.z, b4.w, acc[2][3]);
            acc[3][0] = fmaf(a4.w, b4.x, acc[3][0]);
            acc[3][1] = fmaf(a4.w, b4.y, acc[3][1]);
            acc[3][2] = fmaf(a4.w, b4.z, acc[3][2]);
            acc[3][3] = fmaf(a4.w, b4.w, acc[3][3]);
        }
    }

#pragma unroll
    for (int i = 0; i < 4; ++i) {
        int node = node0 + ty * 4 + i;
        if (node < n) {
            float d = dinv[node];
            float4 o = make_float4(acc[i][0] * d, acc[i][1] * d, acc[i][2] * d, acc[i][3] * d);
            *(float4*)&linS[(size_t)node * HH + tx * 4] = o;
        }
    }
}

// ---------------- gather aggregation + bias + L2norm + ReLU ----------------
// linS rows are pre-scaled by dinv[src]. out = dinv[c]*(linS[c] + sum linS[r]) + b.
// Self term enters the sum UNSCALED (it already carries one dinv[c]); the final
// di* multiply supplies the second factor.  (R9 bug: extra di on self => di^3.)
__global__ void k_gather(const float* __restrict__ linS, const int* __restrict__ csr,
                         const int* __restrict__ rowptr,
                         const float* __restrict__ dinv, const float* __restrict__ b,
                         float* __restrict__ hout, int n) {
    int node = blockIdx.x * (blockDim.x >> 6) + (threadIdx.x >> 6);
    int lane = threadIdx.x & 63;
    if (node >= n) return;
    int start = rowptr[node], end = rowptr[node + 1];
    float di = dinv[node];
    float acc0 = linS[(size_t)node * HH + lane];   // self-loop: dinv[c]*lin[c]
    float acc1 = 0.f, acc2 = 0.f, acc3 = 0.f;
    for (int base = start; base < end; base += 64) {
        int m = end - base; if (m > 64) m = 64;
        int sv = (base + lane < end) ? csr[base + lane] : 0;
        int j = 0;
        for (; j + 7 < m; j += 8) {
            int s0 = __shfl(sv, j, 64);
            int s1 = __shfl(sv, j + 1, 64);
            int s2 = __shfl(sv, j + 2, 64);
            int s3 = __shfl(sv, j + 3, 64);
            int s4 = __shfl(sv, j + 4, 64);
            int s5 = __shfl(sv, j + 5, 64);
            int s6 = __shfl(sv, j + 6, 64);
            int s7 = __shfl(sv, j + 7, 64);
            float v0 = linS[(size_t)s0 * HH + lane];
            float v1 = linS[(size_t)s1 * HH + lane];
            float v2 = linS[(size_t)s2 * HH + lane];
            float v3 = linS[(size_t)s3 * HH + lane];
            float v4 = linS[(size_t)s4 * HH + lane];
            float v5 = linS[(size_t)s5 * HH + lane];
            float v6 = linS[(size_t)s6 * HH + lane];
            float v7 = linS[(size_t)s7 * HH + lane];
            acc0 += v0; acc1 += v1; acc2 += v2; acc3 += v3;
            acc0 += v4; acc1 += v5; acc2 += v6; acc3 += v7;
        }
        for (; j < m; ++j) {
            int s0 = __shfl(sv, j, 64);
            acc0 += linS[(size_t)s0 * HH + lane];
        }
    }
    float v = di * ((acc0 + acc1) + (acc2 + acc3)) + b[lane];
    float ss = v * v;
#pragma unroll
    for (int off = 1; off < 64; off <<= 1) ss += __shfl_xor(ss, off, 64);
    v = v / fmaxf(sqrtf(ss), 1e-12f);
    hout[(size_t)node * HH + lane] = fmaxf(v, 0.f);
}

// ---------------- pooling: parallel over nodes ----------------
__global__ __launch_bounds__(256) void k_pool(const float* __restrict__ node_emb,
                                              const int* __restrict__ batch,
                                              float* __restrict__ sums,
                                              float* __restrict__ cnts, int n) {
    const int NPW = 16;
    int wave = blockIdx.x * 4 + (threadIdx.x >> 6);
    int lane = threadIdx.x & 63;
    int start = wave * NPW;
    if (start >= n) return;
    int end = start + NPW; if (end > n) end = n;
    int cur = batch[start];
    float acc = 0.f;
    int runlen = 0;
    for (int node = start; node < end; ++node) {
        int g = batch[node];
        if (g != cur) {
            atomicAdd(&sums[(size_t)cur * HH + lane], acc);
            if (lane == 0) atomicAdd(&cnts[cur], (float)runlen);
            acc = 0.f; runlen = 0; cur = g;
        }
        acc += node_emb[(size_t)node * HH + lane];
        ++runlen;
    }
    atomicAdd(&sums[(size_t)cur * HH + lane], acc);
    if (lane == 0) atomicAdd(&cnts[cur], (float)runlen);
}

// ---------------- classifier + softmax ----------------
__global__ void k_final2(const float* __restrict__ sums, const float* __restrict__ cnts,
                         const float* __restrict__ Wm, const float* __restrict__ bm,
                         float* __restrict__ logits, float* __restrict__ probs,
                         float* __restrict__ graph_emb) {
    int g = blockIdx.x;
    int lane = threadIdx.x;
    float mean = sums[(size_t)g * HH + lane] / fmaxf(cnts[g], 1.0f);
    graph_emb[(size_t)g * HH + lane] = mean;

    __shared__ float semb[HH];
    __shared__ float slog[16];
    semb[lane] = mean;
    __syncthreads();
    if (lane < 10) {
        float acc = bm[lane];
        for (int k = 0; k < HH; ++k) acc = fmaf(semb[k], Wm[k * 10 + lane], acc);
        slog[lane] = acc;
    }
    __syncthreads();
    if (lane < 10) {
        float mx = -1e30f;
        for (int j = 0; j < 10; ++j) mx = fmaxf(mx, slog[j]);
        float den = 0.f;
        for (int j = 0; j < 10; ++j) den += __expf(slog[j] - mx);
        float lg = slog[lane];
        logits[g * 10 + lane] = lg;
        probs[g * 10 + lane] = __expf(lg - mx) / den;
    }
}

// ---------------- launch ----------------

extern "C" void kernel_launch(void* const* d_in, const int* in_sizes, int n_in,
                              void* d_out, int out_size, void* d_ws, size_t ws_size,
                              hipStream_t stream) {
    const float* x     = (const float*)d_in[0];
    const int*   ei    = (const int*)  d_in[1];
    const int*   batch = (const int*)  d_in[2];
    const float* W1 = (const float*)d_in[3];  const float* b1 = (const float*)d_in[4];
    const float* W2 = (const float*)d_in[5];  const float* b2 = (const float*)d_in[6];
    const float* W3 = (const float*)d_in[7];  const float* b3 = (const float*)d_in[8];
    const float* Wm = (const float*)d_in[9];  const float* bm = (const float*)d_in[10];

    const int N = in_sizes[2];
    const int E = in_sizes[1] / 2;
    const int G = (out_size - N * HH) / (2 * 10 + HH);

    const int* row = ei;
    const int* col = ei + E;

    float* out       = (float*)d_out;
    float* logits    = out;
    float* probs     = out + (size_t)G * 10;
    float* node_emb  = out + (size_t)2 * G * 10;
    float* graph_emb = node_emb + (size_t)N * HH;

    char* w = (char*)d_ws;
    auto alloc = [&](size_t bytes) { char* p = w; w += (bytes + 255) & ~(size_t)255; return p; };
    float* dinv    = (float*)alloc((size_t)N * 4);
    int*   cnt     = (int*)  alloc((size_t)N * 4);
    int*   rowptr  = (int*)  alloc(((size_t)N + 1) * 4);
    int*   head    = (int*)  alloc((size_t)N * 4);
    int*   nxt     = (int*)  alloc((size_t)E * 4);
    int*   partial = (int*)  alloc(1024 * 4);
    float* sums    = (float*)alloc((size_t)G * HH * 4 + (size_t)G * 4);
    float* cnts    = sums + (size_t)G * HH;
    int*   csr     = (int*)  alloc((size_t)E * 4);
    float* lin     = (float*)alloc((size_t)N * HH * 4);
    float* hbuf    = (float*)alloc((size_t)N * HH * 4);

    const int B = 256;
    dim3 blk(B);
    int node_blocks = (N + 3) / 4;
    int gemm_blocks = (N + 63) / 64;
    int nB = (N + B - 1) / B;
    int eB = (E + B - 1) / B;
    int scanB = (N + SCAN_B - 1) / SCAN_B;
    int poolN = G * HH + G;
    int pool_blocks = (N + 63) / 64;

    // CSR build + normalization
    k_init<<<nB, blk, 0, stream>>>(cnt, head, sums, N, poolN);
    k_count_link<<<eB, blk, 0, stream>>>(col, E, cnt, head, nxt);
    k_scan_reduce<<<scanB, dim3(SCAN_B), 0, stream>>>(cnt, N, partial);
    k_scan_partials<<<1, dim3(1024), 0, stream>>>(partial, scanB, rowptr, N);
    k_scan_apply<<<scanB, dim3(SCAN_B), 0, stream>>>(cnt, partial, N, rowptr, dinv);
    k_walk<<<nB, blk, 0, stream>>>(row, head, nxt, rowptr, csr, N);

    // layer 1 (FIN=128)
    k_gemm2<128><<<gemm_blocks, blk, 0, stream>>>(x, W1, dinv, lin, N);
    k_gather<<<node_blocks, blk, 0, stream>>>(lin, csr, rowptr, dinv, b1, hbuf, N);
    // layer 2
    k_gemm2<64><<<gemm_blocks, blk, 0, stream>>>(hbuf, W2, dinv, lin, N);
    k_gather<<<node_blocks, blk, 0, stream>>>(lin, csr, rowptr, dinv, b2, hbuf, N);
    // layer 3 -> node_emb
    k_gemm2<64><<<gemm_blocks, blk, 0, stream>>>(hbuf, W3, dinv, lin, N);
    k_gather<<<node_blocks, blk, 0, stream>>>(lin, csr, rowptr, dinv, b3, node_emb, N);

    // pool + classifier
    k_pool<<<pool_blocks, blk, 0, stream>>>(node_emb, batch, sums, cnts, N);
    k_final2<<<G, dim3(64), 0, stream>>>(sums, cnts, Wm, bm, logits, probs, graph_emb);
}

// Round 11
// 334.090 us; speedup vs baseline: 1.0996x; 1.0963x over previous
//
#include <hip/hip_runtime.h>
#include <math.h>

#define HH 64

// ---------------- init ----------------

__global__ void k_init(int* __restrict__ head, float* __restrict__ sums,
                       int* __restrict__ cursor, int n, int pn) {
    int i = blockIdx.x * blockDim.x + threadIdx.x;
    if (i < n) head[i] = -1;
    if (i < pn) sums[i] = 0.f;
    if (i == 0) *cursor = 0;
}

// ---------------- CSR build ----------------
// linked-list build: ONE atomic stream (exch) + sequential next[] store.
__global__ void k_link(const int* __restrict__ col, int E,
                       int* __restrict__ head, int* __restrict__ next) {
    int e = blockIdx.x * blockDim.x + threadIdx.x;
    if (e >= E) return;
    int c = col[e];
    int prev = atomicExch(&head[c], e);
    next[e] = prev;
}

// thread-per-node: walk list (count) -> wave-prefix alloc -> walk again (write csr).
// Replaces the cnt atomic pass AND the 3-kernel scan.
__global__ __launch_bounds__(256) void k_walk_alloc(const int* __restrict__ row,
                                                    const int* __restrict__ head,
                                                    const int* __restrict__ next,
                                                    int* __restrict__ cursor,
                                                    int* __restrict__ rowptr,
                                                    int* __restrict__ cnt,
                                                    float* __restrict__ dinv,
                                                    int* __restrict__ csr, int n) {
    int node = blockIdx.x * blockDim.x + threadIdx.x;
    int lane = threadIdx.x & 63;
    int len = 0;
    int h = -1;
    if (node < n) {
        h = head[node];
        for (int p = h; p >= 0; p = next[p]) ++len;
        dinv[node] = rsqrtf((float)(len + 1));
    }
    // wave-level exclusive prefix sum of len (one global atomic per wave)
    int incl = len;
#pragma unroll
    for (int off = 1; off < 64; off <<= 1) {
        int t = __shfl_up(incl, off, 64);
        if (lane >= off) incl += t;
    }
    int total = __shfl(incl, 63, 64);
    int base = 0;
    if (lane == 0 && total > 0) base = atomicAdd(cursor, total);
    base = __shfl(base, 0, 64);
    int dst = base + incl - len;
    if (node < n) {
        rowptr[node] = dst;
        cnt[node]    = len;
        for (int p = h; p >= 0; p = next[p]) csr[dst++] = row[p];
    }
}

// ---------------- dense transform: k-chunked register-tiled GEMM ----------------
// output pre-scaled by dinv[node] (normalization factorization)
template<int FIN>
__global__ __launch_bounds__(256, 4) void k_gemm2(const float* __restrict__ x,
                                                  const float* __restrict__ W,
                                                  const float* __restrict__ dinv,
                                                  float* __restrict__ linS, int n) {
    constexpr int KC = 32;
    constexpr int XS = 68;
    __shared__ __align__(16) float Ws[FIN][HH];
    __shared__ __align__(16) float xs_t[KC][XS];
    const int tid = threadIdx.x;
    const int tx = tid & 15;
    const int ty = tid >> 4;
    const int node0 = blockIdx.x * 64;

    for (int i = tid * 4; i < FIN * HH; i += 1024)
        *(float4*)&Ws[0][i] = *(const float4*)&W[i];

    float acc[4][4] = {};

    const int rr0 = tid >> 3;
    const int cc  = (tid & 7) * 4;

    for (int kc = 0; kc < FIN; kc += KC) {
        __syncthreads();
        for (int rr = rr0; rr < 64; rr += 32) {
            float4 v = make_float4(0.f, 0.f, 0.f, 0.f);
            if (node0 + rr < n) v = *(const float4*)&x[(size_t)(node0 + rr) * FIN + kc + cc];
            xs_t[cc + 0][rr] = v.x;
            xs_t[cc + 1][rr] = v.y;
            xs_t[cc + 2][rr] = v.z;
            xs_t[cc + 3][rr] = v.w;
        }
        __syncthreads();
#pragma unroll 4
        for (int k = 0; k < KC; ++k) {
            float4 a4 = *(const float4*)&xs_t[k][ty * 4];
            float4 b4 = *(const float4*)&Ws[kc + k][tx * 4];
            acc[0][0] = fmaf(a4.x, b4.x, acc[0][0]);
            acc[0][1] = fmaf(a4.x, b4.y, acc[0][1]);
            acc[0][2] = fmaf(a4.x, b4.z, acc[0][2]);
            acc[0][3] = fmaf(a4.x, b4.w, acc[0][3]);
            acc[1][0] = fmaf(a4.y, b4.x, acc[1][0]);
            acc[1][1] = fmaf(a4.y, b4.y, acc[1][1]);
            acc[1][2] = fmaf(a4.y, b4.z, acc[1][2]);
            acc[1][3] = fmaf(a4.y, b4.w, acc[1][3]);
            acc[2][0] = fmaf(a4.z, b4.x, acc[2][0]);
            acc[2][1] = fmaf(a4.z, b4.y, acc[2][1]);
            acc[2][2] = fmaf(a4.z, b4.z, acc[2][2]);
            acc[2][3] = fmaf(a4.z, b4.w, acc[2][3]);
            acc[3][0] = fmaf(a4.w, b4.x, acc[3][0]);
            acc[3][1] = fmaf(a4.w, b4.y, acc[3][1]);
            acc[3][2] = fmaf(a4.w, b4.z, acc[3][2]);
            acc[3][3] = fmaf(a4.w, b4.w, acc[3][3]);
        }
    }

#pragma unroll
    for (int i = 0; i < 4; ++i) {
        int node = node0 + ty * 4 + i;
        if (node < n) {
            float d = dinv[node];
            float4 o = make_float4(acc[i][0] * d, acc[i][1] * d, acc[i][2] * d, acc[i][3] * d);
            *(float4*)&linS[(size_t)node * HH + tx * 4] = o;
        }
    }
}

// ---------------- gather aggregation + bias + L2norm + ReLU ----------------
// linS rows pre-scaled by dinv[src]. out = dinv[c]*(linS[c] + sum linS[r]) + b.
__global__ void k_gather(const float* __restrict__ linS, const int* __restrict__ csr,
                         const int* __restrict__ rowptr, const int* __restrict__ cnt,
                         const float* __restrict__ dinv, const float* __restrict__ b,
                         float* __restrict__ hout, int n) {
    int node = blockIdx.x * (blockDim.x >> 6) + (threadIdx.x >> 6);
    int lane = threadIdx.x & 63;
    if (node >= n) return;
    int start = rowptr[node];
    int end = start + cnt[node];
    float di = dinv[node];
    float acc0 = linS[(size_t)node * HH + lane];   // self-loop term (carries one dinv[c])
    float acc1 = 0.f, acc2 = 0.f, acc3 = 0.f;
    for (int base = start; base < end; base += 64) {
        int m = end - base; if (m > 64) m = 64;
        int sv = (base + lane < end) ? csr[base + lane] : 0;
        int j = 0;
        for (; j + 7 < m; j += 8) {
            int s0 = __shfl(sv, j, 64);
            int s1 = __shfl(sv, j + 1, 64);
            int s2 = __shfl(sv, j + 2, 64);
            int s3 = __shfl(sv, j + 3, 64);
            int s4 = __shfl(sv, j + 4, 64);
            int s5 = __shfl(sv, j + 5, 64);
            int s6 = __shfl(sv, j + 6, 64);
            int s7 = __shfl(sv, j + 7, 64);
            float v0 = linS[(size_t)s0 * HH + lane];
            float v1 = linS[(size_t)s1 * HH + lane];
            float v2 = linS[(size_t)s2 * HH + lane];
            float v3 = linS[(size_t)s3 * HH + lane];
            float v4 = linS[(size_t)s4 * HH + lane];
            float v5 = linS[(size_t)s5 * HH + lane];
            float v6 = linS[(size_t)s6 * HH + lane];
            float v7 = linS[(size_t)s7 * HH + lane];
            acc0 += v0; acc1 += v1; acc2 += v2; acc3 += v3;
            acc0 += v4; acc1 += v5; acc2 += v6; acc3 += v7;
        }
        for (; j < m; ++j) {
            int s0 = __shfl(sv, j, 64);
            acc0 += linS[(size_t)s0 * HH + lane];
        }
    }
    float v = di * ((acc0 + acc1) + (acc2 + acc3)) + b[lane];
    float ss = v * v;
#pragma unroll
    for (int off = 1; off < 64; off <<= 1) ss += __shfl_xor(ss, off, 64);
    v = v / fmaxf(sqrtf(ss), 1e-12f);
    hout[(size_t)node * HH + lane] = fmaxf(v, 0.f);
}

// ---------------- pooling: parallel over nodes ----------------
__global__ __launch_bounds__(256) void k_pool(const float* __restrict__ node_emb,
                                              const int* __restrict__ batch,
                                              float* __restrict__ sums,
                                              float* __restrict__ cnts, int n) {
    const int NPW = 16;
    int wave = blockIdx.x * 4 + (threadIdx.x >> 6);
    int lane = threadIdx.x & 63;
    int start = wave * NPW;
    if (start >= n) return;
    int end = start + NPW; if (end > n) end = n;
    int cur = batch[start];
    float acc = 0.f;
    int runlen = 0;
    for (int node = start; node < end; ++node) {
        int g = batch[node];
        if (g != cur) {
            atomicAdd(&sums[(size_t)cur * HH + lane], acc);
            if (lane == 0) atomicAdd(&cnts[cur], (float)runlen);
            acc = 0.f; runlen = 0; cur = g;
        }
        acc += node_emb[(size_t)node * HH + lane];
        ++runlen;
    }
    atomicAdd(&sums[(size_t)cur * HH + lane], acc);
    if (lane == 0) atomicAdd(&cnts[cur], (float)runlen);
}

// ---------------- classifier + softmax ----------------
__global__ void k_final2(const float* __restrict__ sums, const float* __restrict__ cnts,
                         const float* __restrict__ Wm, const float* __restrict__ bm,
                         float* __restrict__ logits, float* __restrict__ probs,
                         float* __restrict__ graph_emb) {
    int g = blockIdx.x;
    int lane = threadIdx.x;
    float mean = sums[(size_t)g * HH + lane] / fmaxf(cnts[g], 1.0f);
    graph_emb[(size_t)g * HH + lane] = mean;

    __shared__ float semb[HH];
    __shared__ float slog[16];
    semb[lane] = mean;
    __syncthreads();
    if (lane < 10) {
        float acc = bm[lane];
        for (int k = 0; k < HH; ++k) acc = fmaf(semb[k], Wm[k * 10 + lane], acc);
        slog[lane] = acc;
    }
    __syncthreads();
    if (lane < 10) {
        float mx = -1e30f;
        for (int j = 0; j < 10; ++j) mx = fmaxf(mx, slog[j]);
        float den = 0.f;
        for (int j = 0; j < 10; ++j) den += __expf(slog[j] - mx);
        float lg = slog[lane];
        logits[g * 10 + lane] = lg;
        probs[g * 10 + lane] = __expf(lg - mx) / den;
    }
}

// ---------------- launch ----------------

extern "C" void kernel_launch(void* const* d_in, const int* in_sizes, int n_in,
                              void* d_out, int out_size, void* d_ws, size_t ws_size,
                              hipStream_t stream) {
    const float* x     = (const float*)d_in[0];
    const int*   ei    = (const int*)  d_in[1];
    const int*   batch = (const int*)  d_in[2];
    const float* W1 = (const float*)d_in[3];  const float* b1 = (const float*)d_in[4];
    const float* W2 = (const float*)d_in[5];  const float* b2 = (const float*)d_in[6];
    const float* W3 = (const float*)d_in[7];  const float* b3 = (const float*)d_in[8];
    const float* Wm = (const float*)d_in[9];  const float* bm = (const float*)d_in[10];

    const int N = in_sizes[2];
    const int E = in_sizes[1] / 2;
    const int G = (out_size - N * HH) / (2 * 10 + HH);

    const int* row = ei;
    const int* col = ei + E;

    float* out       = (float*)d_out;
    float* logits    = out;
    float* probs     = out + (size_t)G * 10;
    float* node_emb  = out + (size_t)2 * G * 10;
    float* graph_emb = node_emb + (size_t)N * HH;

    char* w = (char*)d_ws;
    auto alloc = [&](size_t bytes) { char* p = w; w += (bytes + 255) & ~(size_t)255; return p; };
    float* dinv    = (float*)alloc((size_t)N * 4);
    int*   cnt     = (int*)  alloc((size_t)N * 4);
    int*   rowptr  = (int*)  alloc((size_t)N * 4);
    int*   head    = (int*)  alloc((size_t)N * 4);
    int*   nxt     = (int*)  alloc((size_t)E * 4);
    int*   cursor  = (int*)  alloc(256);
    float* sums    = (float*)alloc((size_t)G * HH * 4 + (size_t)G * 4);
    float* cnts    = sums + (size_t)G * HH;
    int*   csr     = (int*)  alloc((size_t)E * 4);
    float* lin     = (float*)alloc((size_t)N * HH * 4);
    float* hbuf    = (float*)alloc((size_t)N * HH * 4);

    const int B = 256;
    dim3 blk(B);
    int node_blocks = (N + 3) / 4;
    int gemm_blocks = (N + 63) / 64;
    int nB = (N + B - 1) / B;
    int eB = (E + B - 1) / B;
    int poolN = G * HH + G;
    int pool_blocks = (N + 63) / 64;

    // CSR build + normalization (no cnt atomics, no scan)
    k_init<<<nB, blk, 0, stream>>>(head, sums, cursor, N, poolN);
    k_link<<<eB, blk, 0, stream>>>(col, E, head, nxt);
    k_walk_alloc<<<nB, blk, 0, stream>>>(row, head, nxt, cursor, rowptr, cnt, dinv, csr, N);

    // layer 1 (FIN=128)
    k_gemm2<128><<<gemm_blocks, blk, 0, stream>>>(x, W1, dinv, lin, N);
    k_gather<<<node_blocks, blk, 0, stream>>>(lin, csr, rowptr, cnt, dinv, b1, hbuf, N);
    // layer 2
    k_gemm2<64><<<gemm_blocks, blk, 0, stream>>>(hbuf, W2, dinv, lin, N);
    k_gather<<<node_blocks, blk, 0, stream>>>(lin, csr, rowptr, cnt, dinv, b2, hbuf, N);
    // layer 3 -> node_emb
    k_gemm2<64><<<gemm_blocks, blk, 0, stream>>>(hbuf, W3, dinv, lin, N);
    k_gather<<<node_blocks, blk, 0, stream>>>(lin, csr, rowptr, cnt, dinv, b3, node_emb, N);

    // pool + classifier
    k_pool<<<pool_blocks, blk, 0, stream>>>(node_emb, batch, sums, cnts, N);
    k_final2<<<G, dim3(64), 0, stream>>>(sums, cnts, Wm, bm, logits, probs, graph_emb);
}

// Round 12
// 331.500 us; speedup vs baseline: 1.1082x; 1.0078x over previous
//
#include <hip/hip_runtime.h>
#include <math.h>

#define HH 64

// ---------------- init ----------------

__global__ void k_init(int* __restrict__ head, float* __restrict__ sums,
                       int* __restrict__ cursor, int n, int pn) {
    int i = blockIdx.x * blockDim.x + threadIdx.x;
    if (i < n) head[i] = -1;
    if (i < pn) sums[i] = 0.f;
    if (i == 0) *cursor = 0;
}

// ---------------- fused: linked-list build + layer-1 GEMM ----------------
// The CSR link pass (atomic/fabric-bound, ~0% VALU) is independent of the
// layer-1 dense transform (VALU/LDS-bound) -> run both in one kernel so the
// atomic latency hides under GEMM compute. GEMM output is UNSCALED (dinv not
// known yet); layer-1 gather applies dinv[src] per edge instead.
template<int FIN>
__global__ __launch_bounds__(256, 4) void k_link_gemm(const int* __restrict__ col, int E,
                                                      int* __restrict__ head, int* __restrict__ next,
                                                      const float* __restrict__ x,
                                                      const float* __restrict__ W,
                                                      float* __restrict__ lin, int n) {
    constexpr int KC = 32;
    constexpr int XS = 68;
    __shared__ __align__(16) float Ws[FIN][HH];
    __shared__ __align__(16) float xs_t[KC][XS];
    const int tid = threadIdx.x;

    // ---- link: 4 edges per thread (1024 per block), grid covers E ----
    int e0 = blockIdx.x * 1024 + tid;
#pragma unroll
    for (int k = 0; k < 4; ++k) {
        int e = e0 + k * 256;
        if (e < E) {
            int c = col[e];
            int prev = atomicExch(&head[c], e);
            next[e] = prev;
        }
    }

    // ---- gemm ----
    const int tx = tid & 15;
    const int ty = tid >> 4;
    const int node0 = blockIdx.x * 64;
    if (node0 >= n) return;   // edge-only tail blocks (none when grids match)

    for (int i = tid * 4; i < FIN * HH; i += 1024)
        *(float4*)&Ws[0][i] = *(const float4*)&W[i];

    float acc[4][4] = {};
    const int rr0 = tid >> 3;
    const int cc  = (tid & 7) * 4;

    for (int kc = 0; kc < FIN; kc += KC) {
        __syncthreads();
        for (int rr = rr0; rr < 64; rr += 32) {
            float4 v = make_float4(0.f, 0.f, 0.f, 0.f);
            if (node0 + rr < n) v = *(const float4*)&x[(size_t)(node0 + rr) * FIN + kc + cc];
            xs_t[cc + 0][rr] = v.x;
            xs_t[cc + 1][rr] = v.y;
            xs_t[cc + 2][rr] = v.z;
            xs_t[cc + 3][rr] = v.w;
        }
        __syncthreads();
#pragma unroll 4
        for (int k = 0; k < KC; ++k) {
            float4 a4 = *(const float4*)&xs_t[k][ty * 4];
            float4 b4 = *(const float4*)&Ws[kc + k][tx * 4];
            acc[0][0] = fmaf(a4.x, b4.x, acc[0][0]);
            acc[0][1] = fmaf(a4.x, b4.y, acc[0][1]);
            acc[0][2] = fmaf(a4.x, b4.z, acc[0][2]);
            acc[0][3] = fmaf(a4.x, b4.w, acc[0][3]);
            acc[1][0] = fmaf(a4.y, b4.x, acc[1][0]);
            acc[1][1] = fmaf(a4.y, b4.y, acc[1][1]);
            acc[1][2] = fmaf(a4.y, b4.z, acc[1][2]);
            acc[1][3] = fmaf(a4.y, b4.w, acc[1][3]);
            acc[2][0] = fmaf(a4.z, b4.x, acc[2][0]);
            acc[2][1] = fmaf(a4.z, b4.y, acc[2][1]);
            acc[2][2] = fmaf(a4.z, b4.z, acc[2][2]);
            acc[2][3] = fmaf(a4.z, b4.w, acc[2][3]);
            acc[3][0] = fmaf(a4.w, b4.x, acc[3][0]);
            acc[3][1] = fmaf(a4.w, b4.y, acc[3][1]);
            acc[3][2] = fmaf(a4.w, b4.z, acc[3][2]);
            acc[3][3] = fmaf(a4.w, b4.w, acc[3][3]);
        }
    }

#pragma unroll
    for (int i = 0; i < 4; ++i) {
        int node = node0 + ty * 4 + i;
        if (node < n) *(float4*)&lin[(size_t)node * HH + tx * 4] = *(float4*)acc[i];
    }
}

// thread-per-node: walk list (count) -> wave-prefix alloc -> walk again (write csr).
__global__ __launch_bounds__(256) void k_walk_alloc(const int* __restrict__ row,
                                                    const int* __restrict__ head,
                                                    const int* __restrict__ next,
                                                    int* __restrict__ cursor,
                                                    int* __restrict__ rowptr,
                                                    int* __restrict__ cnt,
                                                    float* __restrict__ dinv,
                                                    int* __restrict__ csr, int n) {
    int node = blockIdx.x * blockDim.x + threadIdx.x;
    int lane = threadIdx.x & 63;
    int len = 0;
    int h = -1;
    if (node < n) {
        h = head[node];
        for (int p = h; p >= 0; p = next[p]) ++len;
        dinv[node] = rsqrtf((float)(len + 1));
    }
    int incl = len;
#pragma unroll
    for (int off = 1; off < 64; off <<= 1) {
        int t = __shfl_up(incl, off, 64);
        if (lane >= off) incl += t;
    }
    int total = __shfl(incl, 63, 64);
    int base = 0;
    if (lane == 0 && total > 0) base = atomicAdd(cursor, total);
    base = __shfl(base, 0, 64);
    int dst = base + incl - len;
    if (node < n) {
        rowptr[node] = dst;
        cnt[node]    = len;
        for (int p = h; p >= 0; p = next[p]) csr[dst++] = row[p];
    }
}

// ---------------- dense transform (layers 2-3): pre-scaled by dinv ----------------
template<int FIN>
__global__ __launch_bounds__(256, 4) void k_gemm2(const float* __restrict__ x,
                                                  const float* __restrict__ W,
                                                  const float* __restrict__ dinv,
                                                  float* __restrict__ linS, int n) {
    constexpr int KC = 32;
    constexpr int XS = 68;
    __shared__ __align__(16) float Ws[FIN][HH];
    __shared__ __align__(16) float xs_t[KC][XS];
    const int tid = threadIdx.x;
    const int tx = tid & 15;
    const int ty = tid >> 4;
    const int node0 = blockIdx.x * 64;

    for (int i = tid * 4; i < FIN * HH; i += 1024)
        *(float4*)&Ws[0][i] = *(const float4*)&W[i];

    float acc[4][4] = {};
    const int rr0 = tid >> 3;
    const int cc  = (tid & 7) * 4;

    for (int kc = 0; kc < FIN; kc += KC) {
        __syncthreads();
        for (int rr = rr0; rr < 64; rr += 32) {
            float4 v = make_float4(0.f, 0.f, 0.f, 0.f);
            if (node0 + rr < n) v = *(const float4*)&x[(size_t)(node0 + rr) * FIN + kc + cc];
            xs_t[cc + 0][rr] = v.x;
            xs_t[cc + 1][rr] = v.y;
            xs_t[cc + 2][rr] = v.z;
            xs_t[cc + 3][rr] = v.w;
        }
        __syncthreads();
#pragma unroll 4
        for (int k = 0; k < KC; ++k) {
            float4 a4 = *(const float4*)&xs_t[k][ty * 4];
            float4 b4 = *(const float4*)&Ws[kc + k][tx * 4];
            acc[0][0] = fmaf(a4.x, b4.x, acc[0][0]);
            acc[0][1] = fmaf(a4.x, b4.y, acc[0][1]);
            acc[0][2] = fmaf(a4.x, b4.z, acc[0][2]);
            acc[0][3] = fmaf(a4.x, b4.w, acc[0][3]);
            acc[1][0] = fmaf(a4.y, b4.x, acc[1][0]);
            acc[1][1] = fmaf(a4.y, b4.y, acc[1][1]);
            acc[1][2] = fmaf(a4.y, b4.z, acc[1][2]);
            acc[1][3] = fmaf(a4.y, b4.w, acc[1][3]);
            acc[2][0] = fmaf(a4.z, b4.x, acc[2][0]);
            acc[2][1] = fmaf(a4.z, b4.y, acc[2][1]);
            acc[2][2] = fmaf(a4.z, b4.z, acc[2][2]);
            acc[2][3] = fmaf(a4.z, b4.w, acc[2][3]);
            acc[3][0] = fmaf(a4.w, b4.x, acc[3][0]);
            acc[3][1] = fmaf(a4.w, b4.y, acc[3][1]);
            acc[3][2] = fmaf(a4.w, b4.z, acc[3][2]);
            acc[3][3] = fmaf(a4.w, b4.w, acc[3][3]);
        }
    }

#pragma unroll
    for (int i = 0; i < 4; ++i) {
        int node = node0 + ty * 4 + i;
        if (node < n) {
            float d = dinv[node];
            float4 o = make_float4(acc[i][0] * d, acc[i][1] * d, acc[i][2] * d, acc[i][3] * d);
            *(float4*)&linS[(size_t)node * HH + tx * 4] = o;
        }
    }
}

// ---------------- layer-1 gather: lin unscaled, weight = dinv[src] per edge ----------------
__global__ void k_gather_w(const float* __restrict__ lin, const int* __restrict__ csr,
                           const int* __restrict__ rowptr, const int* __restrict__ cnt,
                           const float* __restrict__ dinv, const float* __restrict__ b,
                           float* __restrict__ hout, int n) {
    int node = blockIdx.x * (blockDim.x >> 6) + (threadIdx.x >> 6);
    int lane = threadIdx.x & 63;
    if (node >= n) return;
    int start = rowptr[node];
    int end = start + cnt[node];
    float di = dinv[node];
    float acc0 = di * lin[(size_t)node * HH + lane];   // self: dinv[c]*lin[c]
    float acc1 = 0.f, acc2 = 0.f, acc3 = 0.f;
    for (int base = start; base < end; base += 64) {
        int m = end - base; if (m > 64) m = 64;
        int   sv = (base + lane < end) ? csr[base + lane] : 0;
        float wv = (base + lane < end) ? dinv[sv] : 0.f;   // L2-hot 200KB
        int j = 0;
        for (; j + 3 < m; j += 4) {
            int s0 = __shfl(sv, j, 64);     float w0 = __shfl(wv, j, 64);
            int s1 = __shfl(sv, j + 1, 64); float w1 = __shfl(wv, j + 1, 64);
            int s2 = __shfl(sv, j + 2, 64); float w2 = __shfl(wv, j + 2, 64);
            int s3 = __shfl(sv, j + 3, 64); float w3 = __shfl(wv, j + 3, 64);
            float v0 = lin[(size_t)s0 * HH + lane];
            float v1 = lin[(size_t)s1 * HH + lane];
            float v2 = lin[(size_t)s2 * HH + lane];
            float v3 = lin[(size_t)s3 * HH + lane];
            acc0 = fmaf(w0, v0, acc0);
            acc1 = fmaf(w1, v1, acc1);
            acc2 = fmaf(w2, v2, acc2);
            acc3 = fmaf(w3, v3, acc3);
        }
        for (; j < m; ++j) {
            int s0 = __shfl(sv, j, 64); float w0 = __shfl(wv, j, 64);
            acc0 = fmaf(w0, lin[(size_t)s0 * HH + lane], acc0);
        }
    }
    float v = di * ((acc0 + acc1) + (acc2 + acc3)) + b[lane];
    float ss = v * v;
#pragma unroll
    for (int off = 1; off < 64; off <<= 1) ss += __shfl_xor(ss, off, 64);
    v = v / fmaxf(sqrtf(ss), 1e-12f);
    hout[(size_t)node * HH + lane] = fmaxf(v, 0.f);
}

// ---------------- layers 2-3 gather: linS pre-scaled ----------------
__global__ void k_gather(const float* __restrict__ linS, const int* __restrict__ csr,
                         const int* __restrict__ rowptr, const int* __restrict__ cnt,
                         const float* __restrict__ dinv, const float* __restrict__ b,
                         float* __restrict__ hout, int n) {
    int node = blockIdx.x * (blockDim.x >> 6) + (threadIdx.x >> 6);
    int lane = threadIdx.x & 63;
    if (node >= n) return;
    int start = rowptr[node];
    int end = start + cnt[node];
    float di = dinv[node];
    float acc0 = linS[(size_t)node * HH + lane];   // self term (carries one dinv[c])
    float acc1 = 0.f, acc2 = 0.f, acc3 = 0.f;
    for (int base = start; base < end; base += 64) {
        int m = end - base; if (m > 64) m = 64;
        int sv = (base + lane < end) ? csr[base + lane] : 0;
        int j = 0;
        for (; j + 7 < m; j += 8) {
            int s0 = __shfl(sv, j, 64);
            int s1 = __shfl(sv, j + 1, 64);
            int s2 = __shfl(sv, j + 2, 64);
            int s3 = __shfl(sv, j + 3, 64);
            int s4 = __shfl(sv, j + 4, 64);
            int s5 = __shfl(sv, j + 5, 64);
            int s6 = __shfl(sv, j + 6, 64);
            int s7 = __shfl(sv, j + 7, 64);
            float v0 = linS[(size_t)s0 * HH + lane];
            float v1 = linS[(size_t)s1 * HH + lane];
            float v2 = linS[(size_t)s2 * HH + lane];
            float v3 = linS[(size_t)s3 * HH + lane];
            float v4 = linS[(size_t)s4 * HH + lane];
            float v5 = linS[(size_t)s5 * HH + lane];
            float v6 = linS[(size_t)s6 * HH + lane];
            float v7 = linS[(size_t)s7 * HH + lane];
            acc0 += v0; acc1 += v1; acc2 += v2; acc3 += v3;
            acc0 += v4; acc1 += v5; acc2 += v6; acc3 += v7;
        }
        for (; j < m; ++j) {
            int s0 = __shfl(sv, j, 64);
            acc0 += linS[(size_t)s0 * HH + lane];
        }
    }
    float v = di * ((acc0 + acc1) + (acc2 + acc3)) + b[lane];
    float ss = v * v;
#pragma unroll
    for (int off = 1; off < 64; off <<= 1) ss += __shfl_xor(ss, off, 64);
    v = v / fmaxf(sqrtf(ss), 1e-12f);
    hout[(size_t)node * HH + lane] = fmaxf(v, 0.f);
}

// ---------------- pooling ----------------
__global__ __launch_bounds__(256) void k_pool(const float* __restrict__ node_emb,
                                              const int* __restrict__ batch,
                                              float* __restrict__ sums,
                                              float* __restrict__ cnts, int n) {
    const int NPW = 16;
    int wave = blockIdx.x * 4 + (threadIdx.x >> 6);
    int lane = threadIdx.x & 63;
    int start = wave * NPW;
    if (start >= n) return;
    int end = start + NPW; if (end > n) end = n;
    int cur = batch[start];
    float acc = 0.f;
    int runlen = 0;
    for (int node = start; node < end; ++node) {
        int g = batch[node];
        if (g != cur) {
            atomicAdd(&sums[(size_t)cur * HH + lane], acc);
            if (lane == 0) atomicAdd(&cnts[cur], (float)runlen);
            acc = 0.f; runlen = 0; cur = g;
        }
        acc += node_emb[(size_t)node * HH + lane];
        ++runlen;
    }
    atomicAdd(&sums[(size_t)cur * HH + lane], acc);
    if (lane == 0) atomicAdd(&cnts[cur], (float)runlen);
}

// ---------------- classifier + softmax ----------------
__global__ void k_final2(const float* __restrict__ sums, const float* __restrict__ cnts,
                         const float* __restrict__ Wm, const float* __restrict__ bm,
                         float* __restrict__ logits, float* __restrict__ probs,
                         float* __restrict__ graph_emb) {
    int g = blockIdx.x;
    int lane = threadIdx.x;
    float mean = sums[(size_t)g * HH + lane] / fmaxf(cnts[g], 1.0f);
    graph_emb[(size_t)g * HH + lane] = mean;

    __shared__ float semb[HH];
    __shared__ float slog[16];
    semb[lane] = mean;
    __syncthreads();
    if (lane < 10) {
        float acc = bm[lane];
        for (int k = 0; k < HH; ++k) acc = fmaf(semb[k], Wm[k * 10 + lane], acc);
        slog[lane] = acc;
    }
    __syncthreads();
    if (lane < 10) {
        float mx = -1e30f;
        for (int j = 0; j < 10; ++j) mx = fmaxf(mx, slog[j]);
        float den = 0.f;
        for (int j = 0; j < 10; ++j) den += __expf(slog[j] - mx);
        float lg = slog[lane];
        logits[g * 10 + lane] = lg;
        probs[g * 10 + lane] = __expf(lg - mx) / den;
    }
}

// ---------------- launch ----------------

extern "C" void kernel_launch(void* const* d_in, const int* in_sizes, int n_in,
                              void* d_out, int out_size, void* d_ws, size_t ws_size,
                              hipStream_t stream) {
    const float* x     = (const float*)d_in[0];
    const int*   ei    = (const int*)  d_in[1];
    const int*   batch = (const int*)  d_in[2];
    const float* W1 = (const float*)d_in[3];  const float* b1 = (const float*)d_in[4];
    const float* W2 = (const float*)d_in[5];  const float* b2 = (const float*)d_in[6];
    const float* W3 = (const float*)d_in[7];  const float* b3 = (const float*)d_in[8];
    const float* Wm = (const float*)d_in[9];  const float* bm = (const float*)d_in[10];

    const int N = in_sizes[2];
    const int E = in_sizes[1] / 2;
    const int G = (out_size - N * HH) / (2 * 10 + HH);

    const int* row = ei;
    const int* col = ei + E;

    float* out       = (float*)d_out;
    float* logits    = out;
    float* probs     = out + (size_t)G * 10;
    float* node_emb  = out + (size_t)2 * G * 10;
    float* graph_emb = node_emb + (size_t)N * HH;

    char* w = (char*)d_ws;
    auto alloc = [&](size_t bytes) { char* p = w; w += (bytes + 255) & ~(size_t)255; return p; };
    float* dinv    = (float*)alloc((size_t)N * 4);
    int*   cnt     = (int*)  alloc((size_t)N * 4);
    int*   rowptr  = (int*)  alloc((size_t)N * 4);
    int*   head    = (int*)  alloc((size_t)N * 4);
    int*   nxt     = (int*)  alloc((size_t)E * 4);
    int*   cursor  = (int*)  alloc(256);
    float* sums    = (float*)alloc((size_t)G * HH * 4 + (size_t)G * 4);
    float* cnts    = sums + (size_t)G * HH;
    int*   csr     = (int*)  alloc((size_t)E * 4);
    float* lin     = (float*)alloc((size_t)N * HH * 4);
    float* hbuf    = (float*)alloc((size_t)N * HH * 4);

    const int B = 256;
    dim3 blk(B);
    int node_blocks = (N + 3) / 4;
    int gemm_blocks = (N + 63) / 64;           // 782; also covers E at 1024 edges/block
    int nB = (N + B - 1) / B;
    int poolN = G * HH + G;
    int pool_blocks = (N + 63) / 64;

    // init + fused(link + layer-1 gemm) + walk
    k_init<<<nB, blk, 0, stream>>>(head, sums, cursor, N, poolN);
    k_link_gemm<128><<<gemm_blocks, blk, 0, stream>>>(col, E, head, nxt, x, W1, lin, N);
    k_walk_alloc<<<nB, blk, 0, stream>>>(row, head, nxt, cursor, rowptr, cnt, dinv, csr, N);

    // layer 1 gather (weights = dinv[src] on the fly)
    k_gather_w<<<node_blocks, blk, 0, stream>>>(lin, csr, rowptr, cnt, dinv, b1, hbuf, N);
    // layer 2
    k_gemm2<64><<<gemm_blocks, blk, 0, stream>>>(hbuf, W2, dinv, lin, N);
    k_gather<<<node_blocks, blk, 0, stream>>>(lin, csr, rowptr, cnt, dinv, b2, hbuf, N);
    // layer 3 -> node_emb
    k_gemm2<64><<<gemm_blocks, blk, 0, stream>>>(hbuf, W3, dinv, lin, N);
    k_gather<<<node_blocks, blk, 0, stream>>>(lin, csr, rowptr, cnt, dinv, b3, node_emb, N);

    // pool + classifier
    k_pool<<<pool_blocks, blk, 0, stream>>>(node_emb, batch, sums, cnts, N);
    k_final2<<<G, dim3(64), 0, stream>>>(sums, cnts, Wm, bm, logits, probs, graph_emb);
}